// Round 1
// baseline (84.973 us; speedup 1.0000x reference)
//
#include <hip/hip_runtime.h>

// GNNComm: out[i,:] = mean_{j!=i} relu(concat(m_i,m_j)@W1^T + b1) @ W2^T + b2
// N=2048, D=8, H=64.
//
// relu(z) = (z+|z|)/2 =>
//   S[i,h] = sum_j relu(a_ih + x_jh) = 0.5*(N*a_ih + SX_h + C_ih),
//   C_ih = sum_j |a_ih + x_jh|, a = X1[i]+b1, x = X2[j], SX = sum_j x_jh
// out[i,d] = 0.5*sum_h (C_ih + SX_h + N*a_ih - 2*relu(a_ih+x_ih)) W2[d,h]
//            / (N-1) + b2[d]
//
// R4: R3's epilogue did 512K device-scope atomicAdds into a 64KB out
// region, 32-way contended per address across 8 non-coherent XCD L2s --
// static model says the pair main loop is only ~7us of VALU, so the
// ~30us gap to the measured ~43us controllable window is attributed to
// that atomic storm (Guideline 12). This version streams each block's
// W2-PROJECTED 64x8 tile (2KB, coalesced) into P[32][2048][8] (2MB in
// ws; R1's lesson was 32MB of UNPROJECTED partials) and reduces with a
// tiny 3rd dispatch. Zero atomics.

#define NN 2048
#define HH 64
#define DD 8

#define ITILES 32          // 32 i-tiles x 64 i
#define JCHUNKS 32         // 32 j-chunks x 64 j
#define JCHUNK (NN / JCHUNKS)
#define INV_SCALE (0.5f / (float)(NN - 1))

// --- K1: A[i,h] = X1[i,h]+b1[h]; X2[i,h] ---
__global__ void prep_kernel(const float* __restrict__ msg,
                            const float* __restrict__ W1,
                            const float* __restrict__ b1,
                            float* __restrict__ A,
                            float* __restrict__ X2) {
    int idx = blockIdx.x * blockDim.x + threadIdx.x;  // 0 .. N*H-1
    int i = idx >> 6;
    int h = idx & 63;
    const float4* m4 = (const float4*)(msg + i * DD);
    const float4* w4 = (const float4*)(W1 + h * (2 * DD));
    float4 m0 = m4[0], m1 = m4[1];
    float4 w0 = w4[0], w1 = w4[1], w2 = w4[2], w3 = w4[3];
    float x1 = m0.x * w0.x + m0.y * w0.y + m0.z * w0.z + m0.w * w0.w
             + m1.x * w1.x + m1.y * w1.y + m1.z * w1.z + m1.w * w1.w;
    float x2 = m0.x * w2.x + m0.y * w2.y + m0.z * w2.z + m0.w * w2.w
             + m1.x * w3.x + m1.y * w3.y + m1.z * w3.z + m1.w * w3.w;
    A[idx]  = x1 + b1[h];
    X2[idx] = x2;
}

// --- K2: pairwise |a+x| + W2 projection -> streaming partial store ---
// Block (it,jc): 64 i x 64 h x 64 j. Thread: hq=tid&15 (4 h's), il=tid>>4 (4 i's).
__global__ void __launch_bounds__(256, 4)
pair_fused(const float* __restrict__ A,
           const float* __restrict__ X2,
           const float* __restrict__ W2,
           const float* __restrict__ b2,
           float* __restrict__ P) {
    __shared__ float4 sX2[JCHUNK * 16];   // staged chunk: [64 j][16 hq] = 16KB
    __shared__ float  T[64][68];          // per-block tile, padded
    __shared__ float4 sSXv[16];           // chunk column-sums of X2

    int it = blockIdx.x & (ITILES - 1);
    int jc = blockIdx.x >> 5;
    int hq = threadIdx.x & 15;
    int il = threadIdx.x >> 4;
    int h0 = hq * 4;
    int i0 = it * 64 + il * 4;
    bool des = (jc == it);                // diagonal block: owns per-i terms

    // stage X2 chunk (coalesced float4 loads)
    {
        const float4* X2v = (const float4*)X2 + jc * JCHUNK * 16;
#pragma unroll
        for (int r = 0; r < 4; ++r) {
            int t = threadIdx.x + r * 256;
            sX2[t] = X2v[t];
        }
    }

    float a[4][4];
#pragma unroll
    for (int k = 0; k < 4; ++k) {
        float4 av = *(const float4*)&A[(i0 + k) * HH + h0];
        a[k][0] = av.x; a[k][1] = av.y; a[k][2] = av.z; a[k][3] = av.w;
    }
    float acc[4][4];
#pragma unroll
    for (int k = 0; k < 4; ++k)
#pragma unroll
        for (int hh = 0; hh < 4; ++hh)
            acc[k][hh] = 0.f;

    __syncthreads();

#pragma unroll 4
    for (int j = 0; j < JCHUNK; ++j) {
        float4 x = sX2[j * 16 + hq];
#pragma unroll
        for (int k = 0; k < 4; ++k) {
            acc[k][0] += __builtin_fabsf(a[k][0] + x.x);
            acc[k][1] += __builtin_fabsf(a[k][1] + x.y);
            acc[k][2] += __builtin_fabsf(a[k][2] + x.z);
            acc[k][3] += __builtin_fabsf(a[k][3] + x.w);
        }
    }

    const float* sX2f = (const float*)sX2;

    // chunk column-sums (wave-0 tail loop; stall hidden by 4 blocks/CU)
    if (threadIdx.x < 64) {
        float s0 = 0.f, s1 = 0.f, s2 = 0.f, s3 = 0.f;
#pragma unroll 8
        for (int j = 0; j < JCHUNK; j += 4) {
            s0 += sX2f[(j + 0) * 64 + threadIdx.x];
            s1 += sX2f[(j + 1) * 64 + threadIdx.x];
            s2 += sX2f[(j + 2) * 64 + threadIdx.x];
            s3 += sX2f[(j + 3) * 64 + threadIdx.x];
        }
        ((float*)sSXv)[threadIdx.x] = (s0 + s1) + (s2 + s3);
    }

    // write tile to LDS; diagonal block folds in N*a - 2*relu(a + x_i)
#pragma unroll
    for (int k = 0; k < 4; ++k) {
        float t0 = acc[k][0], t1 = acc[k][1], t2 = acc[k][2], t3 = acc[k][3];
        if (des) {
            int jl = il * 4 + k;  // local j index == local i index on diagonal
            float z0 = a[k][0] + sX2f[jl * 64 + h0 + 0];
            float z1 = a[k][1] + sX2f[jl * 64 + h0 + 1];
            float z2 = a[k][2] + sX2f[jl * 64 + h0 + 2];
            float z3 = a[k][3] + sX2f[jl * 64 + h0 + 3];
            t0 += (float)NN * a[k][0] - 2.f * (z0 > 0.f ? z0 : 0.f);
            t1 += (float)NN * a[k][1] - 2.f * (z1 > 0.f ? z1 : 0.f);
            t2 += (float)NN * a[k][2] - 2.f * (z2 > 0.f ? z2 : 0.f);
            t3 += (float)NN * a[k][3] - 2.f * (z3 > 0.f ? z3 : 0.f);
        }
        *(float4*)&T[il * 4 + k][h0] = make_float4(t0, t1, t2, t3);
    }
    __syncthreads();

    // project (T + sSX) onto W2 rows -> coalesced partial store to P
    {
        int iL = threadIdx.x >> 3;        // 0..31
        int d  = threadIdx.x & 7;
        const float4* w2v = (const float4*)W2;  // [8][16]
        float s0 = 0.f, s1 = 0.f, c = 0.f;
#pragma unroll
        for (int hb = 0; hb < 16; ++hb) {
            float4 w  = w2v[d * 16 + hb];
            float4 t0 = *(const float4*)&T[iL][hb * 4];
            float4 t1 = *(const float4*)&T[iL + 32][hb * 4];
            float4 sx = sSXv[hb];
            s0 += t0.x * w.x + t0.y * w.y + t0.z * w.z + t0.w * w.w;
            s1 += t1.x * w.x + t1.y * w.y + t1.z * w.z + t1.w * w.w;
            c  += sx.x * w.x + sx.y * w.y + sx.z * w.z + sx.w * w.w;
        }
        float v0 = (s0 + c) * INV_SCALE;
        float v1 = (s1 + c) * INV_SCALE;
        if (des) {
            float bv = b2[d];
            v0 += bv;
            v1 += bv;
        }
        // P[jc][it*64 + iL][d]: (iL*8+d) == tid, ((iL+32)*8+d) == tid+256
        float* Pblk = P + ((size_t)jc * NN + (size_t)it * 64) * DD;
        Pblk[threadIdx.x]       = v0;
        Pblk[threadIdx.x + 256] = v1;
    }
}

// --- K3: out[i,d] = sum_jc P[jc][i][d] ---
__global__ void reduce_kernel(const float* __restrict__ P,
                              float* __restrict__ out) {
    int idx = blockIdx.x * blockDim.x + threadIdx.x;  // 0 .. N*D-1
    float s = 0.f;
#pragma unroll
    for (int jc = 0; jc < JCHUNKS; ++jc)
        s += P[jc * (NN * DD) + idx];
    out[idx] = s;
}

extern "C" void kernel_launch(void* const* d_in, const int* in_sizes, int n_in,
                              void* d_out, int out_size, void* d_ws, size_t ws_size,
                              hipStream_t stream) {
    const float* msg = (const float*)d_in[0];  // [N, 8]
    const float* W1  = (const float*)d_in[1];  // [64, 16]
    const float* b1  = (const float*)d_in[2];  // [64]
    const float* W2  = (const float*)d_in[3];  // [8, 64]
    const float* b2  = (const float*)d_in[4];  // [8]
    float* out = (float*)d_out;                // [N, 8]

    float* ws = (float*)d_ws;
    float* A  = ws;                 // N*H
    float* X2 = ws + NN * HH;       // N*H
    float* P  = ws + 2 * NN * HH;   // 32 * N * D = 2MB of partials

    prep_kernel<<<(NN * HH) / 256, 256, 0, stream>>>(msg, W1, b1, A, X2);
    pair_fused<<<ITILES * JCHUNKS, 256, 0, stream>>>(A, X2, W2, b2, P);
    reduce_kernel<<<(NN * DD) / 256, 256, 0, stream>>>(P, out);
}